// Round 1
// baseline (1129.348 us; speedup 1.0000x reference)
//
#include <hip/hip_runtime.h>

// Problem constants (fixed by reference setup_inputs)
constexpr int NN   = 50000;    // nodes
constexpr int NE   = 600000;   // edges
constexpr int NRBF = 50;       // rbf features
constexpr int DIM  = 128;      // embedding dim
constexpr float CUT = 5.0f;
constexpr float PI_F = 3.14159265358979323846f;

constexpr int EPB = 64;        // edges per block (edge kernel)
constexpr int NPB = 64;        // nodes per block (node kernel)

// ---------------------------------------------------------------------------
// Kernel 1: per-edge  x_edge = (rbf @ W_e^T + b_e) * cc(dist)
//           msg      = emb[node_type[src]] * x_edge
//           atomic scatter-sum into xi[dst]   (xi aliases d_out, pre-zeroed)
// Tile: 64 edges x 128 dims per 256-thread block; thread = 8 edges x 4 dims.
// ---------------------------------------------------------------------------
__global__ __launch_bounds__(256)
void edge_scatter_kernel(const float* __restrict__ rbf,
                         const float* __restrict__ dist,
                         const int*   __restrict__ src,
                         const int*   __restrict__ dst,
                         const int*   __restrict__ node_type,
                         const float* __restrict__ emb,
                         const float* __restrict__ W_e,
                         const float* __restrict__ b_e,
                         float*       __restrict__ xi)
{
    __shared__ float rbf_s[EPB][NRBF + 2];   // +2 pad: conflict-free staging writes
    __shared__ float WeT_s[NRBF][DIM];       // W_e transposed: [k][d]
    __shared__ float cc_s[EPB];
    __shared__ int   dst_s[EPB];
    __shared__ int   embrow_s[EPB];

    const int t  = threadIdx.x;
    const int e0 = blockIdx.x * EPB;

    // Stage W_e^T: thread (d = t&127) copies half its row (k split by t>>7).
    {
        const int d  = t & (DIM - 1);
        const int k0 = (t >> 7) * (NRBF / 2);
        for (int k = k0; k < k0 + NRBF / 2; ++k)
            WeT_s[k][d] = W_e[d * NRBF + k];
    }
    // Stage rbf tile, fully coalesced global reads.
    for (int idx = t; idx < EPB * NRBF; idx += 256) {
        const int el = idx / NRBF;
        const int k  = idx - el * NRBF;
        rbf_s[el][k] = rbf[e0 * NRBF + idx];
    }
    // Per-edge scalars.
    if (t < EPB) {
        const int e = e0 + t;
        const float dd = dist[e];
        const float w  = 0.5f * (__cosf(dd * (PI_F / CUT)) + 1.0f);
        cc_s[t]     = (dd < CUT) ? w : 0.0f;
        dst_s[t]    = dst[e];
        embrow_s[t] = node_type[src[e]];
    }
    __syncthreads();

    const int tx = t & 31;        // dim group
    const int ty = t >> 5;        // edge group
    const int d4 = tx * 4;
    const int e8 = ty * 8;

    float acc[8][4] = {};
    for (int k = 0; k < NRBF; ++k) {
        const float4 w4 = *(const float4*)&WeT_s[k][d4];
        #pragma unroll
        for (int i = 0; i < 8; ++i) {
            const float r = rbf_s[e8 + i][k];   // 2 addrs per wave -> broadcast
            acc[i][0] = fmaf(r, w4.x, acc[i][0]);
            acc[i][1] = fmaf(r, w4.y, acc[i][1]);
            acc[i][2] = fmaf(r, w4.z, acc[i][2]);
            acc[i][3] = fmaf(r, w4.w, acc[i][3]);
        }
    }

    const float4 be4 = *(const float4*)&b_e[d4];
    #pragma unroll
    for (int i = 0; i < 8; ++i) {
        const int el = e8 + i;
        const float cc = cc_s[el];
        if (cc != 0.0f) {   // dist >= cutoff => msg exactly 0, skip atomics (~17% of edges)
            const float4 em4 = *(const float4*)&emb[embrow_s[el] * DIM + d4];
            float* base = &xi[(size_t)dst_s[el] * DIM + d4];
            atomicAdd(base + 0, (acc[i][0] + be4.x) * cc * em4.x);
            atomicAdd(base + 1, (acc[i][1] + be4.y) * cc * em4.y);
            atomicAdd(base + 2, (acc[i][2] + be4.z) * cc * em4.z);
            atomicAdd(base + 3, (acc[i][3] + be4.w) * cc * em4.w);
        }
    }
}

// ---------------------------------------------------------------------------
// Kernel 2: out[n] = [x_nodes[n] | xi[n]] @ W_c^T + b_c
// xi lives in `out` (written by kernel 1). In-place is safe: each block reads
// only its own 64 rows (all reads complete before the post-staging barrier of
// the last chunk), then overwrites exactly those rows in the epilogue.
// Tile: 64 nodes x 128 dims per block; K=256 in chunks of 16.
// ---------------------------------------------------------------------------
__global__ __launch_bounds__(256)
void node_combine_kernel(const float* __restrict__ x_nodes,
                         const float* __restrict__ W_c,
                         const float* __restrict__ b_c,
                         float*       __restrict__ out)
{
    __shared__ float Xs[NPB][17];   // +1 pad
    __shared__ float Ws[16][DIM];   // W_c^T chunk: [j][d]

    const int t  = threadIdx.x;
    const int n0 = blockIdx.x * NPB;
    const int tx = t & 31;
    const int ty = t >> 5;
    const int d4 = tx * 4;
    const int ny = ty * 8;

    float acc[8][4] = {};

    for (int jc = 0; jc < 16; ++jc) {
        const int jbase = jc * 16;
        const float* Xsrc = (jc < 8) ? (x_nodes + jbase) : (out + (jbase - DIM));

        __syncthreads();  // protect Xs/Ws from previous iteration's readers
        for (int idx = t; idx < NPB * 16; idx += 256) {
            const int nl = idx >> 4;
            const int jj = idx & 15;
            const int n  = n0 + nl;
            Xs[nl][jj] = (n < NN) ? Xsrc[(size_t)n * DIM + jj] : 0.0f;
        }
        {
            const int d = t & (DIM - 1);
            for (int jr = (t >> 7); jr < 16; jr += 2)
                Ws[jr][d] = W_c[d * (2 * DIM) + jbase + jr];
        }
        __syncthreads();

        #pragma unroll
        for (int jj = 0; jj < 16; ++jj) {
            const float4 w4 = *(const float4*)&Ws[jj][d4];
            #pragma unroll
            for (int i = 0; i < 8; ++i) {
                const float x = Xs[ny + i][jj];
                acc[i][0] = fmaf(x, w4.x, acc[i][0]);
                acc[i][1] = fmaf(x, w4.y, acc[i][1]);
                acc[i][2] = fmaf(x, w4.z, acc[i][2]);
                acc[i][3] = fmaf(x, w4.w, acc[i][3]);
            }
        }
    }

    const float4 bc4 = *(const float4*)&b_c[d4];
    #pragma unroll
    for (int i = 0; i < 8; ++i) {
        const int n = n0 + ny + i;
        if (n < NN) {
            float4 o;
            o.x = acc[i][0] + bc4.x;
            o.y = acc[i][1] + bc4.y;
            o.z = acc[i][2] + bc4.z;
            o.w = acc[i][3] + bc4.w;
            *(float4*)&out[(size_t)n * DIM + d4] = o;
        }
    }
}

// ---------------------------------------------------------------------------
extern "C" void kernel_launch(void* const* d_in, const int* in_sizes, int n_in,
                              void* d_out, int out_size, void* d_ws, size_t ws_size,
                              hipStream_t stream)
{
    const int*   node_type = (const int*)  d_in[0];   // [NN]
    const float* x_nodes   = (const float*)d_in[1];   // [NN, 128]
    const int*   src       = (const int*)  d_in[2];   // [NE]
    const int*   dst       = (const int*)  d_in[3];   // [NE]
    const float* rbf       = (const float*)d_in[4];   // [NE, 50]
    const float* dist      = (const float*)d_in[5];   // [NE]
    const float* emb       = (const float*)d_in[6];   // [100, 128]
    const float* W_e       = (const float*)d_in[7];   // [128, 50]
    const float* b_e       = (const float*)d_in[8];   // [128]
    const float* W_c       = (const float*)d_in[9];   // [128, 256]
    const float* b_c       = (const float*)d_in[10];  // [128]
    float* out = (float*)d_out;                       // [NN, 128]

    // out doubles as the x_integrated accumulator; zero it (d_out is poisoned).
    hipMemsetAsync(out, 0, (size_t)NN * DIM * sizeof(float), stream);

    edge_scatter_kernel<<<NE / EPB, 256, 0, stream>>>(
        rbf, dist, src, dst, node_type, emb, W_e, b_e, out);

    node_combine_kernel<<<(NN + NPB - 1) / NPB, 256, 0, stream>>>(
        x_nodes, W_c, b_c, out);
}

// Round 2
// 1096.502 us; speedup vs baseline: 1.0300x; 1.0300x over previous
//
#include <hip/hip_runtime.h>
#include <hip/hip_bf16.h>

// Problem constants (fixed by reference setup_inputs)
constexpr int NN   = 50000;    // nodes
constexpr int NE   = 600000;   // edges
constexpr int NRBF = 50;       // rbf features
constexpr int DIM  = 128;      // embedding dim
constexpr float CUT = 5.0f;
constexpr float PI_F = 3.14159265358979323846f;

constexpr int CAP = 64;        // bucket capacity per node (Poisson(10) degree; P(>64)~1e-30)

// Workspace layout (int units). All offsets 16B-aligned.
constexpr int OFF_DEG  = 0;                    // [NN] int
constexpr int OFF_OVFC = NN;                   // [1]  int  (memset covers deg+ovfc)
constexpr int OFF_EID  = 50176;                // [NN*CAP] int
constexpr int OFF_OVF  = OFF_EID + NN * CAP;   // [NE] int
constexpr int OFF_XI   = OFF_OVF + NE;         // [NN*DIM] float
// total = 10,250,176 ints = 41.0 MB

typedef __attribute__((ext_vector_type(4))) float f32x4;
typedef __attribute__((ext_vector_type(8))) short short8;

// ---------------------------------------------------------------------------
// Kernel 1: bucket edges by dst (active edges only: dist < CUT).
// ---------------------------------------------------------------------------
__global__ __launch_bounds__(256)
void build_buckets(const int* __restrict__ dst, const float* __restrict__ dist,
                   int* __restrict__ deg, int* __restrict__ eid,
                   int* __restrict__ ovf, int* __restrict__ ovf_cnt)
{
    const int e = blockIdx.x * 256 + threadIdx.x;
    if (e >= NE) return;
    if (dist[e] < CUT) {
        const int n = dst[e];
        const int pos = atomicAdd(&deg[n], 1);
        if (pos < CAP) eid[n * CAP + pos] = e;
        else           ovf[atomicAdd(ovf_cnt, 1)] = e;
    }
}

// ---------------------------------------------------------------------------
// Kernel 2: gather-recompute. For each node n:
//   xi[n][d] = sum_{e: dst=e->n, dist<CUT} cc(e) * (rbf[e]·W_e[d,:] + b_e[d]) * emb[nt[src[e]]][d]
// Block = 256 threads = 2 node-lanes x 128 dims. Thread owns dim d; W_e row d
// lives in 50 VGPRs; rbf row is wave-uniform (readfirstlane'd edge id) ->
// scalar/broadcast loads. No atomics, no LDS, no barriers.
// ---------------------------------------------------------------------------
__device__ __forceinline__
float edge_contrib(int e, int d, const float* __restrict__ rbf,
                   const float* __restrict__ dist, const int* __restrict__ src,
                   const int* __restrict__ node_type, const float* __restrict__ emb,
                   const float* __restrict__ w, float bed)
{
    const float dd = dist[e];
    const int trow = node_type[src[e]];
    const float cc = 0.5f * (__cosf(dd * (PI_F / CUT)) + 1.0f);
    const float2* rr = (const float2*)(rbf + (size_t)e * NRBF);  // 8B-aligned (200*e)
    float dot = bed;
    #pragma unroll
    for (int q = 0; q < NRBF / 2; ++q) {
        const float2 r2 = rr[q];
        dot = fmaf(r2.x, w[2 * q],     dot);
        dot = fmaf(r2.y, w[2 * q + 1], dot);
    }
    return dot * cc * emb[trow * DIM + d];
}

__global__ __launch_bounds__(256)
void gather_nodes(const float* __restrict__ rbf, const float* __restrict__ dist,
                  const int* __restrict__ src, const int* __restrict__ dst,
                  const int* __restrict__ node_type, const float* __restrict__ emb,
                  const float* __restrict__ W_e, const float* __restrict__ b_e,
                  const int* __restrict__ deg, const int* __restrict__ eid,
                  const int* __restrict__ ovf, const int* __restrict__ ovf_cnt,
                  float* __restrict__ xi)
{
    const int t = threadIdx.x;
    const int d = t & (DIM - 1);
    const int half = t >> 7;            // which node-lane (wave-uniform)

    float w[NRBF];
    #pragma unroll
    for (int k = 0; k < NRBF; ++k) w[k] = W_e[d * NRBF + k];
    const float bed = b_e[d];
    const int ocnt = ovf_cnt[0];

    for (int n = blockIdx.x * 2 + half; n < NN; n += gridDim.x * 2) {
        const int dn = deg[n];
        const int degn = dn < CAP ? dn : CAP;
        float acc = 0.0f;
        int e = (degn > 0) ? __builtin_amdgcn_readfirstlane(eid[n * CAP]) : 0;
        for (int j = 0; j < degn; ++j) {
            const int e_nxt = (j + 1 < degn)
                ? __builtin_amdgcn_readfirstlane(eid[n * CAP + j + 1]) : 0;
            acc += edge_contrib(e, d, rbf, dist, src, node_type, emb, w, bed);
            e = e_nxt;
        }
        // Overflow fallback (deg > CAP) — ocnt is 0 for this input; kept for safety.
        for (int j = 0; j < ocnt; ++j) {
            const int eo = __builtin_amdgcn_readfirstlane(ovf[j]);
            if (dst[eo] == n)
                acc += edge_contrib(eo, d, rbf, dist, src, node_type, emb, w, bed);
        }
        xi[(size_t)n * DIM + d] = acc;
    }
}

// ---------------------------------------------------------------------------
// Kernel 3: out[n] = [x_nodes[n] | xi[n]] @ W_c^T + b_c   via bf16 MFMA.
// Block tile: 64 nodes x 128 dims, K=256 in 4 chunks of 64.
// A = rows of [x_nodes|xi] (fp32 -> bf16 at staging), B = W_c rows (already [dim][k]).
// LDS stride 72 bf16 -> 2-way bank conflicts only (free).
// ---------------------------------------------------------------------------
__global__ __launch_bounds__(256)
void combine_mfma(const float* __restrict__ x_nodes, const float* __restrict__ xi,
                  const float* __restrict__ W_c, const float* __restrict__ b_c,
                  float* __restrict__ out)
{
    __shared__ __hip_bfloat16 As[64][72];
    __shared__ __hip_bfloat16 Bs[128][72];

    const int t  = threadIdx.x;
    const int wv = t >> 6;              // wave 0..3 -> node strip wv*16
    const int l  = t & 63;
    const int n0 = blockIdx.x * 64;

    f32x4 acc[8] = {};                  // 8 dim-tiles of 16

    for (int kc = 0; kc < 4; ++kc) {
        const int kb = kc * 64;
        if (kc) __syncthreads();
        // ---- stage A: 64 rows x 64 k (16 floats per thread) ----
        {
            const float* S = (kc < 2) ? (x_nodes + kb) : (xi + (kb - DIM));
            const int r  = t >> 2;
            const int c0 = (t & 3) * 16;
            const int n  = n0 + r;
            float4 v[4];
            if (n < NN) {
                const float4* p = (const float4*)(S + (size_t)n * DIM + c0);
                v[0] = p[0]; v[1] = p[1]; v[2] = p[2]; v[3] = p[3];
            } else {
                v[0] = v[1] = v[2] = v[3] = make_float4(0.f, 0.f, 0.f, 0.f);
            }
            __hip_bfloat16* dp = &As[r][c0];
            #pragma unroll
            for (int q = 0; q < 4; ++q) {
                dp[q * 4 + 0] = __float2bfloat16(v[q].x);
                dp[q * 4 + 1] = __float2bfloat16(v[q].y);
                dp[q * 4 + 2] = __float2bfloat16(v[q].z);
                dp[q * 4 + 3] = __float2bfloat16(v[q].w);
            }
        }
        // ---- stage B: 128 rows x 64 k (32 floats per thread) ----
        {
            const int dch = t >> 1;
            const int c0  = (t & 1) * 32;
            const float4* p = (const float4*)(W_c + (size_t)dch * (2 * DIM) + kb + c0);
            __hip_bfloat16* dp = &Bs[dch][c0];
            #pragma unroll
            for (int q = 0; q < 8; ++q) {
                const float4 v = p[q];
                dp[q * 4 + 0] = __float2bfloat16(v.x);
                dp[q * 4 + 1] = __float2bfloat16(v.y);
                dp[q * 4 + 2] = __float2bfloat16(v.z);
                dp[q * 4 + 3] = __float2bfloat16(v.w);
            }
        }
        __syncthreads();
        // ---- compute: 2 k-steps of 32 ----
        #pragma unroll
        for (int s = 0; s < 2; ++s) {
            const int ko = s * 32 + (l >> 4) * 8;      // 16B-aligned (ko mult of 8)
            const short8 af = *(const short8*)&As[wv * 16 + (l & 15)][ko];
            #pragma unroll
            for (int nt = 0; nt < 8; ++nt) {
                const short8 bf = *(const short8*)&Bs[nt * 16 + (l & 15)][ko];
                acc[nt] = __builtin_amdgcn_mfma_f32_16x16x32_bf16(af, bf, acc[nt], 0, 0, 0);
            }
        }
    }

    // Epilogue: C/D layout col=lane&15 (dim), row=(lane>>4)*4+reg (node).
    const int col = l & 15;
    const int rq  = (l >> 4) * 4;
    #pragma unroll
    for (int nt = 0; nt < 8; ++nt) {
        const int dim = nt * 16 + col;
        const float bc = b_c[dim];
        #pragma unroll
        for (int r = 0; r < 4; ++r) {
            const int node = n0 + wv * 16 + rq + r;
            if (node < NN)
                out[(size_t)node * DIM + dim] = acc[nt][r] + bc;
        }
    }
}

// ---------------------------------------------------------------------------
extern "C" void kernel_launch(void* const* d_in, const int* in_sizes, int n_in,
                              void* d_out, int out_size, void* d_ws, size_t ws_size,
                              hipStream_t stream)
{
    const int*   node_type = (const int*)  d_in[0];
    const float* x_nodes   = (const float*)d_in[1];
    const int*   src       = (const int*)  d_in[2];
    const int*   dst       = (const int*)  d_in[3];
    const float* rbf       = (const float*)d_in[4];
    const float* dist      = (const float*)d_in[5];
    const float* emb       = (const float*)d_in[6];
    const float* W_e       = (const float*)d_in[7];
    const float* b_e       = (const float*)d_in[8];
    const float* W_c       = (const float*)d_in[9];
    const float* b_c       = (const float*)d_in[10];
    float* out = (float*)d_out;

    int*   deg     = (int*)d_ws + OFF_DEG;
    int*   ovf_cnt = (int*)d_ws + OFF_OVFC;
    int*   eid     = (int*)d_ws + OFF_EID;
    int*   ovf     = (int*)d_ws + OFF_OVF;
    float* xi      = (float*)((int*)d_ws + OFF_XI);

    hipMemsetAsync(d_ws, 0, (NN + 1) * sizeof(int), stream);  // deg + ovf_cnt

    build_buckets<<<(NE + 255) / 256, 256, 0, stream>>>(dst, dist, deg, eid, ovf, ovf_cnt);

    gather_nodes<<<2048, 256, 0, stream>>>(rbf, dist, src, dst, node_type, emb,
                                           W_e, b_e, deg, eid, ovf, ovf_cnt, xi);

    combine_mfma<<<(NN + 63) / 64, 256, 0, stream>>>(x_nodes, xi, W_c, b_c, out);
}

// Round 4
// 369.272 us; speedup vs baseline: 3.0583x; 2.9694x over previous
//
#include <hip/hip_runtime.h>
#include <hip/hip_bf16.h>

// Problem constants (fixed by reference setup_inputs)
constexpr int NN   = 50000;    // nodes
constexpr int NE   = 600000;   // edges
constexpr int NRBF = 50;       // rbf features
constexpr int DIM  = 128;      // embedding dim
constexpr float CUT = 5.0f;
constexpr float PI_F = 3.14159265358979323846f;

constexpr int CAP = 64;        // bucket capacity (Poisson(10) degree; P(>64)~1e-30)

// Workspace layout (byte offsets, 256B-aligned). Total ~182.6 MB.
constexpr size_t OFF_DEG  = 0;                          // [NN] int
constexpr size_t OFF_OVFC = OFF_DEG  + (size_t)NN * 4;  // [1] int (memset covers both)
constexpr size_t OFF_EID  = 200960;                     // [NN*CAP] int (12.8 MB)
constexpr size_t OFF_OVF  = OFF_EID  + (size_t)NN * CAP * 4;   // [NE] int
constexpr size_t OFF_MSG  = OFF_OVF  + (size_t)NE * 4;         // [NE*DIM] bf16 (153.6 MB)
constexpr size_t OFF_XI   = OFF_MSG  + (size_t)NE * DIM * 2;   // [NN*DIM] bf16 (12.8 MB)

typedef __attribute__((ext_vector_type(4))) float f32x4;
typedef __attribute__((ext_vector_type(8))) short short8;

__device__ __forceinline__ float bf2f(unsigned short u) {
    return __uint_as_float(((unsigned int)u) << 16);
}

// ---------------------------------------------------------------------------
// Kernel 1: bucket active edges (dist < CUT) by dst.
// ---------------------------------------------------------------------------
__global__ __launch_bounds__(256)
void build_buckets(const int* __restrict__ dst, const float* __restrict__ dist,
                   int* __restrict__ deg, int* __restrict__ eid,
                   int* __restrict__ ovf, int* __restrict__ ovf_cnt)
{
    const int e = blockIdx.x * 256 + threadIdx.x;
    if (e >= NE) return;
    if (dist[e] < CUT) {
        const int n = dst[e];
        const int pos = atomicAdd(&deg[n], 1);
        if (pos < CAP) eid[n * CAP + pos] = e;
        else           ovf[atomicAdd(ovf_cnt, 1)] = e;
    }
}

// ---------------------------------------------------------------------------
// Kernel 2 (Phase A): per-edge message via bf16 MFMA, stored to msg[] (bf16).
//   msg[e][d] = (rbf[e]·W_e[d,:] + b_e[d]) * cc(e) * emb[nt[src[e]]][d]
// Tile: 64 edges x 128 dims, K=50 zero-padded to 64, 2 k-steps of 32.
// ---------------------------------------------------------------------------
__global__ __launch_bounds__(256)
void edge_msg_kernel(const float* __restrict__ rbf, const float* __restrict__ dist,
                     const int* __restrict__ src, const int* __restrict__ node_type,
                     const float* __restrict__ emb, const float* __restrict__ W_e,
                     const float* __restrict__ b_e, __hip_bfloat16* __restrict__ msg)
{
    __shared__ unsigned short As[64][72];    // edges x k (bf16 bits)
    __shared__ unsigned short Bs[128][72];   // dims  x k (bf16 bits)
    __shared__ float cc_s[64];
    __shared__ int   embrow_s[64];

    const int t  = threadIdx.x;
    const int e0 = blockIdx.x * 64;

    // ---- stage A: rbf rows (4 threads/row, float2-interleaved) ----
    {
        const int r = t >> 2, c = t & 3;
        const float2* row = (const float2*)(rbf + (size_t)(e0 + r) * NRBF);
        #pragma unroll
        for (int s = 0; s < 7; ++s) {
            const int idx = c + 4 * s;
            if (idx < 25) {
                const float2 v = row[idx];
                As[r][2 * idx]     = __bfloat16_as_ushort(__float2bfloat16(v.x));
                As[r][2 * idx + 1] = __bfloat16_as_ushort(__float2bfloat16(v.y));
            }
        }
        // zero pad k = 50..63 (+ harmless 64,65)
        *(ushort2*)&As[r][50 + 2 * c] = make_ushort2(0, 0);
        *(ushort2*)&As[r][58 + 2 * c] = make_ushort2(0, 0);
    }
    // ---- stage B: W_e rows [d][k] (2 threads/row) ----
    {
        const int r = t >> 1, c = t & 1;
        const float2* row = (const float2*)(W_e + (size_t)r * NRBF);
        #pragma unroll
        for (int s = 0; s < 13; ++s) {
            const int idx = c + 2 * s;
            if (idx < 25) {
                const float2 v = row[idx];
                Bs[r][2 * idx]     = __bfloat16_as_ushort(__float2bfloat16(v.x));
                Bs[r][2 * idx + 1] = __bfloat16_as_ushort(__float2bfloat16(v.y));
            }
        }
        #pragma unroll
        for (int q = 0; q < 4; ++q)
            *(ushort2*)&Bs[r][50 + 4 * q + 2 * c] = make_ushort2(0, 0);
    }
    // ---- per-edge scalars ----
    if (t < 64) {
        const int e = e0 + t;
        const float dd = dist[e];
        const float w  = 0.5f * (__cosf(dd * (PI_F / CUT)) + 1.0f);
        cc_s[t]     = (dd < CUT) ? w : 0.0f;
        embrow_s[t] = node_type[src[e]];
    }
    __syncthreads();

    const int wv = t >> 6, l = t & 63;
    f32x4 acc[8] = {};
    #pragma unroll
    for (int s = 0; s < 2; ++s) {
        const int ko = s * 32 + (l >> 4) * 8;
        const short8 af = *(const short8*)&As[wv * 16 + (l & 15)][ko];
        #pragma unroll
        for (int nt = 0; nt < 8; ++nt) {
            const short8 bf = *(const short8*)&Bs[nt * 16 + (l & 15)][ko];
            acc[nt] = __builtin_amdgcn_mfma_f32_16x16x32_bf16(af, bf, acc[nt], 0, 0, 0);
        }
    }

    // Epilogue: D row = edge (within strip), col = dim.
    const int col = l & 15;
    const int rq  = (l >> 4) * 4;
    float be[8];
    #pragma unroll
    for (int nt = 0; nt < 8; ++nt) be[nt] = b_e[nt * 16 + col];

    #pragma unroll
    for (int r = 0; r < 4; ++r) {
        const int el = wv * 16 + rq + r;
        const float cc = cc_s[el];
        if (cc != 0.0f) {
            const int erow = embrow_s[el];
            __hip_bfloat16* mrow = msg + (size_t)(e0 + el) * DIM;
            #pragma unroll
            for (int nt = 0; nt < 8; ++nt) {
                const int dim = nt * 16 + col;
                const float v = (acc[nt][r] + be[nt]) * cc * emb[(size_t)erow * DIM + dim];
                mrow[dim] = __float2bfloat16(v);
            }
        }
    }
}

// ---------------------------------------------------------------------------
// Kernel 3 (Phase B): gather-sum msg rows per node. One wave per node; lane
// holds 2 dims (bf16x2 = 4B). eids loaded coalescedly once, broadcast via
// __shfl (register op) -> msg-row loads are independent and pipeline.
// ---------------------------------------------------------------------------
__global__ __launch_bounds__(256)
void gather_sum(const __hip_bfloat16* __restrict__ msg, const int* __restrict__ deg,
                const int* __restrict__ eid, const int* __restrict__ ovf,
                const int* __restrict__ ovf_cnt, const int* __restrict__ dst,
                __hip_bfloat16* __restrict__ xi)
{
    const int t    = threadIdx.x;
    const int lane = t & 63;
    const int n    = blockIdx.x * 4 + (t >> 6);
    if (n >= NN) return;

    const int dn   = deg[n];
    const int degn = dn < CAP ? dn : CAP;
    int eidv = 0;
    if (lane < degn) eidv = eid[n * CAP + lane];

    float ax = 0.0f, ay = 0.0f;
    int j = 0;
    for (; j + 4 <= degn; j += 4) {
        const int ea = __shfl(eidv, j);
        const int eb = __shfl(eidv, j + 1);
        const int ec = __shfl(eidv, j + 2);
        const int ed = __shfl(eidv, j + 3);
        const ushort2 va = ((const ushort2*)(msg + (size_t)ea * DIM))[lane];
        const ushort2 vb = ((const ushort2*)(msg + (size_t)eb * DIM))[lane];
        const ushort2 vc = ((const ushort2*)(msg + (size_t)ec * DIM))[lane];
        const ushort2 vd = ((const ushort2*)(msg + (size_t)ed * DIM))[lane];
        ax += bf2f(va.x) + bf2f(vb.x) + bf2f(vc.x) + bf2f(vd.x);
        ay += bf2f(va.y) + bf2f(vb.y) + bf2f(vc.y) + bf2f(vd.y);
    }
    for (; j < degn; ++j) {
        const int e = __shfl(eidv, j);
        const ushort2 v = ((const ushort2*)(msg + (size_t)e * DIM))[lane];
        ax += bf2f(v.x);
        ay += bf2f(v.y);
    }
    // Overflow fallback (deg > CAP): empty for this input, kept for generality.
    const int ocnt = ovf_cnt[0];
    for (j = 0; j < ocnt; ++j) {
        const int e = ovf[j];
        if (dst[e] == n) {
            const ushort2 v = ((const ushort2*)(msg + (size_t)e * DIM))[lane];
            ax += bf2f(v.x);
            ay += bf2f(v.y);
        }
    }

    ushort2 st;
    st.x = __bfloat16_as_ushort(__float2bfloat16(ax));
    st.y = __bfloat16_as_ushort(__float2bfloat16(ay));
    ((ushort2*)(xi + (size_t)n * DIM))[lane] = st;
}

// ---------------------------------------------------------------------------
// Kernel 4: out[n] = [x_nodes[n] | xi[n]] @ W_c^T + b_c   via bf16 MFMA.
// xi is already bf16; x_nodes converted at staging.
// ---------------------------------------------------------------------------
__global__ __launch_bounds__(256)
void combine_mfma(const float* __restrict__ x_nodes, const __hip_bfloat16* __restrict__ xi,
                  const float* __restrict__ W_c, const float* __restrict__ b_c,
                  float* __restrict__ out)
{
    __shared__ unsigned short As[64][72];
    __shared__ unsigned short Bs[128][72];

    const int t  = threadIdx.x;
    const int wv = t >> 6;
    const int l  = t & 63;
    const int n0 = blockIdx.x * 64;

    f32x4 acc[8] = {};

    for (int kc = 0; kc < 4; ++kc) {
        const int kb = kc * 64;
        if (kc) __syncthreads();
        // ---- stage A rows ----
        {
            const int r  = t >> 2;
            const int c0 = (t & 3) * 16;
            const int n  = n0 + r;
            if (kc < 2) {   // x_nodes, fp32 -> bf16
                float4 v[4];
                if (n < NN) {
                    const float4* p = (const float4*)(x_nodes + (size_t)n * DIM + kb + c0);
                    v[0] = p[0]; v[1] = p[1]; v[2] = p[2]; v[3] = p[3];
                } else {
                    v[0] = v[1] = v[2] = v[3] = make_float4(0.f, 0.f, 0.f, 0.f);
                }
                unsigned short* dp = &As[r][c0];
                #pragma unroll
                for (int q = 0; q < 4; ++q) {
                    dp[q * 4 + 0] = __bfloat16_as_ushort(__float2bfloat16(v[q].x));
                    dp[q * 4 + 1] = __bfloat16_as_ushort(__float2bfloat16(v[q].y));
                    dp[q * 4 + 2] = __bfloat16_as_ushort(__float2bfloat16(v[q].z));
                    dp[q * 4 + 3] = __bfloat16_as_ushort(__float2bfloat16(v[q].w));
                }
            } else {        // xi, already bf16: copy 16 bf16 = 32 B (2 x int4)
                int4 v0 = make_int4(0, 0, 0, 0), v1 = make_int4(0, 0, 0, 0);
                if (n < NN) {
                    const int4* p = (const int4*)(xi + (size_t)n * DIM + (kb - DIM) + c0);
                    v0 = p[0];
                    v1 = p[1];
                }
                *(int4*)&As[r][c0]     = v0;
                *(int4*)&As[r][c0 + 8] = v1;
            }
        }
        // ---- stage B: W_c rows [d][k], fp32 -> bf16 ----
        {
            const int dch = t >> 1;
            const int c0  = (t & 1) * 32;
            const float4* p = (const float4*)(W_c + (size_t)dch * (2 * DIM) + kb + c0);
            unsigned short* dp = &Bs[dch][c0];
            #pragma unroll
            for (int q = 0; q < 8; ++q) {
                const float4 v = p[q];
                dp[q * 4 + 0] = __bfloat16_as_ushort(__float2bfloat16(v.x));
                dp[q * 4 + 1] = __bfloat16_as_ushort(__float2bfloat16(v.y));
                dp[q * 4 + 2] = __bfloat16_as_ushort(__float2bfloat16(v.z));
                dp[q * 4 + 3] = __bfloat16_as_ushort(__float2bfloat16(v.w));
            }
        }
        __syncthreads();
        #pragma unroll
        for (int s = 0; s < 2; ++s) {
            const int ko = s * 32 + (l >> 4) * 8;
            const short8 af = *(const short8*)&As[wv * 16 + (l & 15)][ko];
            #pragma unroll
            for (int nt = 0; nt < 8; ++nt) {
                const short8 bf = *(const short8*)&Bs[nt * 16 + (l & 15)][ko];
                acc[nt] = __builtin_amdgcn_mfma_f32_16x16x32_bf16(af, bf, acc[nt], 0, 0, 0);
            }
        }
    }

    const int col = l & 15;
    const int rq  = (l >> 4) * 4;
    #pragma unroll
    for (int nt = 0; nt < 8; ++nt) {
        const int dim = nt * 16 + col;
        const float bc = b_c[dim];
        #pragma unroll
        for (int r = 0; r < 4; ++r) {
            const int node = n0 + wv * 16 + rq + r;
            if (node < NN)
                out[(size_t)node * DIM + dim] = acc[nt][r] + bc;
        }
    }
}

// ---------------------------------------------------------------------------
extern "C" void kernel_launch(void* const* d_in, const int* in_sizes, int n_in,
                              void* d_out, int out_size, void* d_ws, size_t ws_size,
                              hipStream_t stream)
{
    const int*   node_type = (const int*)  d_in[0];
    const float* x_nodes   = (const float*)d_in[1];
    const int*   src       = (const int*)  d_in[2];
    const int*   dst       = (const int*)  d_in[3];
    const float* rbf       = (const float*)d_in[4];
    const float* dist      = (const float*)d_in[5];
    const float* emb       = (const float*)d_in[6];
    const float* W_e       = (const float*)d_in[7];
    const float* b_e       = (const float*)d_in[8];
    const float* W_c       = (const float*)d_in[9];
    const float* b_c       = (const float*)d_in[10];
    float* out = (float*)d_out;

    char* ws = (char*)d_ws;
    int*            deg     = (int*)(ws + OFF_DEG);
    int*            ovf_cnt = (int*)(ws + OFF_OVFC);
    int*            eid     = (int*)(ws + OFF_EID);
    int*            ovf     = (int*)(ws + OFF_OVF);
    __hip_bfloat16* msg     = (__hip_bfloat16*)(ws + OFF_MSG);
    __hip_bfloat16* xi      = (__hip_bfloat16*)(ws + OFF_XI);

    hipMemsetAsync(deg, 0, (NN + 1) * sizeof(int), stream);

    build_buckets<<<(NE + 255) / 256, 256, 0, stream>>>(dst, dist, deg, eid, ovf, ovf_cnt);

    edge_msg_kernel<<<NE / 64, 256, 0, stream>>>(rbf, dist, src, node_type, emb,
                                                 W_e, b_e, msg);

    gather_sum<<<(NN + 3) / 4, 256, 0, stream>>>(msg, deg, eid, ovf, ovf_cnt, dst, xi);

    combine_mfma<<<(NN + 63) / 64, 256, 0, stream>>>(x_nodes, xi, W_c, b_c, out);
}

// Round 5
// 357.618 us; speedup vs baseline: 3.1580x; 1.0326x over previous
//
#include <hip/hip_runtime.h>
#include <hip/hip_bf16.h>

// Problem constants (fixed by reference setup_inputs)
constexpr int NN   = 50000;    // nodes
constexpr int NE   = 600000;   // edges
constexpr int NRBF = 50;       // rbf features
constexpr int DIM  = 128;      // embedding dim
constexpr float CUT = 5.0f;
constexpr float PI_F = 3.14159265358979323846f;

constexpr int CAP = 64;        // bucket capacity (Poisson(~10) active degree)

// Workspace layout (byte offsets, 256B-aligned). Total ~182.6 MB.
constexpr size_t OFF_DEG  = 0;                          // [NN] int
constexpr size_t OFF_OVFC = OFF_DEG  + (size_t)NN * 4;  // [1] int (memset covers both)
constexpr size_t OFF_EID  = 200960;                     // [NN*CAP] int (12.8 MB)
constexpr size_t OFF_OVF  = OFF_EID  + (size_t)NN * CAP * 4;   // [NE] int
constexpr size_t OFF_MSG  = OFF_OVF  + (size_t)NE * 4;         // [NE*DIM] bf16 (153.6 MB)
constexpr size_t OFF_XI   = OFF_MSG  + (size_t)NE * DIM * 2;   // [NN*DIM] bf16 (12.8 MB)

// msg rows use a PERMUTED dim layout: row position p holds dim
//   delta(p) = 16*(p&7) + (p>>3),  inverse  pi(d) = (d&15)*8 + (d>>4).
// This makes the MFMA-D epilogue store 16 B contiguous per lane.

typedef __attribute__((ext_vector_type(4))) float f32x4;
typedef __attribute__((ext_vector_type(8))) short short8;

__device__ __forceinline__ float bf2f(unsigned short u) {
    return __uint_as_float(((unsigned int)u) << 16);
}
__device__ __forceinline__ unsigned short f2bf(float f) {
    return __bfloat16_as_ushort(__float2bfloat16(f));
}

// ---------------------------------------------------------------------------
// Kernel 1: bucket active edges (dist < CUT) by dst.
// ---------------------------------------------------------------------------
__global__ __launch_bounds__(256)
void build_buckets(const int* __restrict__ dst, const float* __restrict__ dist,
                   int* __restrict__ deg, int* __restrict__ eid,
                   int* __restrict__ ovf, int* __restrict__ ovf_cnt)
{
    const int e = blockIdx.x * 256 + threadIdx.x;
    if (e >= NE) return;
    if (dist[e] < CUT) {
        const int n = dst[e];
        const int pos = atomicAdd(&deg[n], 1);
        if (pos < CAP) eid[n * CAP + pos] = e;
        else           ovf[atomicAdd(ovf_cnt, 1)] = e;
    }
}

// ---------------------------------------------------------------------------
// Kernel 2 (Phase A): per-edge message via bf16 MFMA -> msg[] (bf16, permuted).
//   msg[e][pi(d)] = (rbf[e]·W_e[d,:] + b_e[d]) * cc(e) * emb[nt[src[e]]][d]
// Block: 4 tiles of 64 edges. W_e staged once per block. Epilogue stores are
// 16 B/lane contiguous thanks to the permuted row layout.
// ---------------------------------------------------------------------------
__global__ __launch_bounds__(256)
void edge_msg_kernel(const float* __restrict__ rbf, const float* __restrict__ dist,
                     const int* __restrict__ src, const int* __restrict__ node_type,
                     const float* __restrict__ emb, const float* __restrict__ W_e,
                     const float* __restrict__ b_e, __hip_bfloat16* __restrict__ msg)
{
    __shared__ unsigned short As[64][72];    // edges x k (bf16 bits)
    __shared__ unsigned short Bs[128][72];   // dims  x k (bf16 bits)
    __shared__ float cc_s[64];
    __shared__ int   embrow_s[64];

    const int t  = threadIdx.x;
    const int wv = t >> 6, l = t & 63;
    const int col = l & 15;
    const int rq  = (l >> 4) * 4;

    // ---- stage B once: W_e rows [d][k], bf16-pair packed writes ----
    {
        const int r = t >> 1, c = t & 1;
        const float2* row = (const float2*)(W_e + (size_t)r * NRBF);
        #pragma unroll
        for (int s = 0; s < 13; ++s) {
            const int idx = c + 2 * s;
            if (idx < 25) {
                const float2 v = row[idx];
                *(ushort2*)&Bs[r][2 * idx] = make_ushort2(f2bf(v.x), f2bf(v.y));
            }
        }
        #pragma unroll
        for (int q = 0; q < 4; ++q)
            *(ushort2*)&Bs[r][50 + 4 * q + 2 * c] = make_ushort2(0, 0);
    }

    float be[8];
    #pragma unroll
    for (int nt = 0; nt < 8; ++nt) be[nt] = b_e[nt * 16 + col];

    for (int tile = 0; tile < 4; ++tile) {
        const int e0 = (blockIdx.x * 4 + tile) * 64;
        if (e0 >= NE) break;
        if (tile) __syncthreads();   // prev tile's MFMA/epilogue reads done

        // ---- stage A: rbf rows, bf16-pair packed writes (2-way banks: free) ----
        {
            const int r = t >> 2, c = t & 3;
            const float2* row = (const float2*)(rbf + (size_t)(e0 + r) * NRBF);
            #pragma unroll
            for (int s = 0; s < 7; ++s) {
                const int idx = c + 4 * s;
                if (idx < 25) {
                    const float2 v = row[idx];
                    *(ushort2*)&As[r][2 * idx] = make_ushort2(f2bf(v.x), f2bf(v.y));
                }
            }
            *(ushort2*)&As[r][50 + 2 * c] = make_ushort2(0, 0);
            *(ushort2*)&As[r][58 + 2 * c] = make_ushort2(0, 0);
        }
        if (t < 64) {
            const int e = e0 + t;
            const float dd = dist[e];
            const float w  = 0.5f * (__cosf(dd * (PI_F / CUT)) + 1.0f);
            cc_s[t]     = (dd < CUT) ? w : 0.0f;
            embrow_s[t] = node_type[src[e]];
        }
        __syncthreads();

        // ---- MFMA: 2 k-steps of 32 ----
        f32x4 acc[8] = {};
        #pragma unroll
        for (int s = 0; s < 2; ++s) {
            const int ko = s * 32 + (l >> 4) * 8;
            const short8 af = *(const short8*)&As[wv * 16 + (l & 15)][ko];
            #pragma unroll
            for (int nt = 0; nt < 8; ++nt) {
                const short8 bf = *(const short8*)&Bs[nt * 16 + (l & 15)][ko];
                acc[nt] = __builtin_amdgcn_mfma_f32_16x16x32_bf16(af, bf, acc[nt], 0, 0, 0);
            }
        }

        // ---- epilogue: permuted row -> one dwordx4 store per edge-row ----
        #pragma unroll
        for (int r = 0; r < 4; ++r) {
            const int el = wv * 16 + rq + r;
            const float cc = cc_s[el];
            if (cc != 0.0f) {
                const int erow = embrow_s[el];
                unsigned int w[4];
                #pragma unroll
                for (int q = 0; q < 4; ++q) {
                    const float v0 = (acc[2 * q][r]     + be[2 * q])     * cc *
                                     emb[(size_t)erow * DIM + (2 * q) * 16 + col];
                    const float v1 = (acc[2 * q + 1][r] + be[2 * q + 1]) * cc *
                                     emb[(size_t)erow * DIM + (2 * q + 1) * 16 + col];
                    w[q] = (unsigned int)f2bf(v0) | ((unsigned int)f2bf(v1) << 16);
                }
                // positions p = nt + 8*col -> ushort offset 8*col, 16 B contiguous
                int4* dp = (int4*)(msg + (size_t)(e0 + el) * DIM + 8 * col);
                *dp = make_int4((int)w[0], (int)w[1], (int)w[2], (int)w[3]);
            }
        }
    }
}

// ---------------------------------------------------------------------------
// Kernel 3 (Phase B): gather-sum permuted msg rows per node (1 wave / node).
// Lane accumulates permuted positions 2*lane, 2*lane+1; a 4-shuffle unpermute
// restores normal dim order before the coalesced xi store.
// ---------------------------------------------------------------------------
__global__ __launch_bounds__(256)
void gather_sum(const __hip_bfloat16* __restrict__ msg, const int* __restrict__ deg,
                const int* __restrict__ eid, const int* __restrict__ ovf,
                const int* __restrict__ ovf_cnt, const int* __restrict__ dst,
                __hip_bfloat16* __restrict__ xi)
{
    const int t    = threadIdx.x;
    const int lane = t & 63;
    const int n    = blockIdx.x * 4 + (t >> 6);
    if (n >= NN) return;

    const int dn   = deg[n];
    const int degn = dn < CAP ? dn : CAP;
    int eidv = 0;
    if (lane < degn) eidv = eid[n * CAP + lane];

    float ax = 0.0f, ay = 0.0f;
    int j = 0;
    for (; j + 4 <= degn; j += 4) {
        const int ea = __shfl(eidv, j);
        const int eb = __shfl(eidv, j + 1);
        const int ec = __shfl(eidv, j + 2);
        const int ed = __shfl(eidv, j + 3);
        const ushort2 va = ((const ushort2*)(msg + (size_t)ea * DIM))[lane];
        const ushort2 vb = ((const ushort2*)(msg + (size_t)eb * DIM))[lane];
        const ushort2 vc = ((const ushort2*)(msg + (size_t)ec * DIM))[lane];
        const ushort2 vd = ((const ushort2*)(msg + (size_t)ed * DIM))[lane];
        ax += bf2f(va.x) + bf2f(vb.x) + bf2f(vc.x) + bf2f(vd.x);
        ay += bf2f(va.y) + bf2f(vb.y) + bf2f(vc.y) + bf2f(vd.y);
    }
    for (; j < degn; ++j) {
        const int e = __shfl(eidv, j);
        const ushort2 v = ((const ushort2*)(msg + (size_t)e * DIM))[lane];
        ax += bf2f(v.x);
        ay += bf2f(v.y);
    }
    // Overflow fallback (deg > CAP): empty for this input, kept for generality.
    const int ocnt = ovf_cnt[0];
    for (j = 0; j < ocnt; ++j) {
        const int e = ovf[j];
        if (dst[e] == n) {
            const ushort2 v = ((const ushort2*)(msg + (size_t)e * DIM))[lane];
            ax += bf2f(v.x);
            ay += bf2f(v.y);
        }
    }

    // Unpermute: this lane stores dims d0=2*lane, d1=2*lane+1.
    // dim d lives at position pi(d) = (d&15)*8 + (d>>4): p_a for d0, p_a+8 for d1.
    const int d0  = 2 * lane;
    const int p_a = ((d0 & 15) << 3) + (d0 >> 4);
    const int s0  = p_a >> 1;          // source lane for d0 (component p_a&1)
    const int cmp = p_a & 1;
    const float A1 = __shfl(ax, s0);
    const float B1 = __shfl(ay, s0);
    const float A2 = __shfl(ax, s0 + 4);   // p_a+8 -> lane s0+4, same component
    const float B2 = __shfl(ay, s0 + 4);
    const float va = cmp ? B1 : A1;
    const float vb = cmp ? B2 : A2;

    ((ushort2*)(xi + (size_t)n * DIM))[lane] = make_ushort2(f2bf(va), f2bf(vb));
}

// ---------------------------------------------------------------------------
// Kernel 4: out[n] = [x_nodes[n] | xi[n]] @ W_c^T + b_c   via bf16 MFMA.
// xi is bf16 in NORMAL dim order; x_nodes converted at staging.
// ---------------------------------------------------------------------------
__global__ __launch_bounds__(256)
void combine_mfma(const float* __restrict__ x_nodes, const __hip_bfloat16* __restrict__ xi,
                  const float* __restrict__ W_c, const float* __restrict__ b_c,
                  float* __restrict__ out)
{
    __shared__ unsigned short As[64][72];
    __shared__ unsigned short Bs[128][72];

    const int t  = threadIdx.x;
    const int wv = t >> 6;
    const int l  = t & 63;
    const int n0 = blockIdx.x * 64;

    f32x4 acc[8] = {};

    for (int kc = 0; kc < 4; ++kc) {
        const int kb = kc * 64;
        if (kc) __syncthreads();
        // ---- stage A rows ----
        {
            const int r  = t >> 2;
            const int c0 = (t & 3) * 16;
            const int n  = n0 + r;
            if (kc < 2) {   // x_nodes, fp32 -> bf16
                float4 v[4];
                if (n < NN) {
                    const float4* p = (const float4*)(x_nodes + (size_t)n * DIM + kb + c0);
                    v[0] = p[0]; v[1] = p[1]; v[2] = p[2]; v[3] = p[3];
                } else {
                    v[0] = v[1] = v[2] = v[3] = make_float4(0.f, 0.f, 0.f, 0.f);
                }
                unsigned short* dp = &As[r][c0];
                #pragma unroll
                for (int q = 0; q < 4; ++q) {
                    *(ushort2*)&dp[q * 4]     = make_ushort2(f2bf(v[q].x), f2bf(v[q].y));
                    *(ushort2*)&dp[q * 4 + 2] = make_ushort2(f2bf(v[q].z), f2bf(v[q].w));
                }
            } else {        // xi, already bf16: copy 16 bf16 = 32 B (2 x int4)
                int4 v0 = make_int4(0, 0, 0, 0), v1 = make_int4(0, 0, 0, 0);
                if (n < NN) {
                    const int4* p = (const int4*)(xi + (size_t)n * DIM + (kb - DIM) + c0);
                    v0 = p[0];
                    v1 = p[1];
                }
                *(int4*)&As[r][c0]     = v0;
                *(int4*)&As[r][c0 + 8] = v1;
            }
        }
        // ---- stage B: W_c rows [d][k], fp32 -> bf16 ----
        {
            const int dch = t >> 1;
            const int c0  = (t & 1) * 32;
            const float4* p = (const float4*)(W_c + (size_t)dch * (2 * DIM) + kb + c0);
            unsigned short* dp = &Bs[dch][c0];
            #pragma unroll
            for (int q = 0; q < 8; ++q) {
                const float4 v = p[q];
                *(ushort2*)&dp[q * 4]     = make_ushort2(f2bf(v.x), f2bf(v.y));
                *(ushort2*)&dp[q * 4 + 2] = make_ushort2(f2bf(v.z), f2bf(v.w));
            }
        }
        __syncthreads();
        #pragma unroll
        for (int s = 0; s < 2; ++s) {
            const int ko = s * 32 + (l >> 4) * 8;
            const short8 af = *(const short8*)&As[wv * 16 + (l & 15)][ko];
            #pragma unroll
            for (int nt = 0; nt < 8; ++nt) {
                const short8 bf = *(const short8*)&Bs[nt * 16 + (l & 15)][ko];
                acc[nt] = __builtin_amdgcn_mfma_f32_16x16x32_bf16(af, bf, acc[nt], 0, 0, 0);
            }
        }
    }

    const int col = l & 15;
    const int rq  = (l >> 4) * 4;
    #pragma unroll
    for (int nt = 0; nt < 8; ++nt) {
        const int dim = nt * 16 + col;
        const float bc = b_c[dim];
        #pragma unroll
        for (int r = 0; r < 4; ++r) {
            const int node = n0 + wv * 16 + rq + r;
            if (node < NN)
                out[(size_t)node * DIM + dim] = acc[nt][r] + bc;
        }
    }
}

// ---------------------------------------------------------------------------
extern "C" void kernel_launch(void* const* d_in, const int* in_sizes, int n_in,
                              void* d_out, int out_size, void* d_ws, size_t ws_size,
                              hipStream_t stream)
{
    const int*   node_type = (const int*)  d_in[0];
    const float* x_nodes   = (const float*)d_in[1];
    const int*   src       = (const int*)  d_in[2];
    const int*   dst       = (const int*)  d_in[3];
    const float* rbf       = (const float*)d_in[4];
    const float* dist      = (const float*)d_in[5];
    const float* emb       = (const float*)d_in[6];
    const float* W_e       = (const float*)d_in[7];
    const float* b_e       = (const float*)d_in[8];
    const float* W_c       = (const float*)d_in[9];
    const float* b_c       = (const float*)d_in[10];
    float* out = (float*)d_out;

    char* ws = (char*)d_ws;
    int*            deg     = (int*)(ws + OFF_DEG);
    int*            ovf_cnt = (int*)(ws + OFF_OVFC);
    int*            eid     = (int*)(ws + OFF_EID);
    int*            ovf     = (int*)(ws + OFF_OVF);
    __hip_bfloat16* msg     = (__hip_bfloat16*)(ws + OFF_MSG);
    __hip_bfloat16* xi      = (__hip_bfloat16*)(ws + OFF_XI);

    hipMemsetAsync(deg, 0, (NN + 1) * sizeof(int), stream);

    build_buckets<<<(NE + 255) / 256, 256, 0, stream>>>(dst, dist, deg, eid, ovf, ovf_cnt);

    edge_msg_kernel<<<(NE / 64 + 3) / 4, 256, 0, stream>>>(rbf, dist, src, node_type, emb,
                                                           W_e, b_e, msg);

    gather_sum<<<(NN + 3) / 4, 256, 0, stream>>>(msg, deg, eid, ovf, ovf_cnt, dst, xi);

    combine_mfma<<<(NN + 63) / 64, 256, 0, stream>>>(x_nodes, xi, W_c, b_c, out);
}

// Round 6
// 355.316 us; speedup vs baseline: 3.1784x; 1.0065x over previous
//
#include <hip/hip_runtime.h>
#include <hip/hip_bf16.h>

// Problem constants (fixed by reference setup_inputs)
constexpr int NN   = 50000;    // nodes
constexpr int NE   = 600000;   // edges
constexpr int NRBF = 50;       // rbf features
constexpr int DIM  = 128;      // embedding dim
constexpr float CUT = 5.0f;
constexpr float PI_F = 3.14159265358979323846f;

constexpr int CAP = 32;        // bucket capacity (active degree ~Poisson(10); P(>32)~1e-9, ovf fallback)

// Workspace layout (byte offsets). Total 180.3 MB (<= R5's proven 181.8 MB).
constexpr size_t OFF_DEG   = 0;                               // [NN] int
constexpr size_t OFF_OVFC  = (size_t)NN * 4;                  // [1] int (memset covers both)
constexpr size_t OFF_EID   = 200960;                          // [NN*CAP] int (6.4 MB)
constexpr size_t OFF_OVF   = OFF_EID  + (size_t)NN * CAP * 4; // [NE] int
constexpr size_t OFF_CC    = OFF_OVF  + (size_t)NE * 4;       // [NE] float
constexpr size_t OFF_EROW  = OFF_CC   + (size_t)NE * 4;       // [NE] int (-1 = inactive)
constexpr size_t OFF_WAUG  = OFF_EROW + (size_t)NE * 4;       // [128*64] bf16 (16 KB)
constexpr size_t OFF_EPERM = OFF_WAUG + 128 * 64 * 2;         // [100*128] bf16 permuted (25.6 KB)
constexpr size_t OFF_MSG   = 13843200;                        // [NE*128] bf16 permuted (153.6 MB)
constexpr size_t OFF_XI    = OFF_MSG  + (size_t)NE * DIM * 2; // [NN*128] bf16 normal order (12.8 MB)

// msg/emb_perm PERMUTED layout: position p holds dim delta(p) = 16*(p&7) + (p>>3).
// Lane c's positions 8c..8c+7 <-> dims {16q + c} = exactly its MFMA-D column across nt.

typedef __attribute__((ext_vector_type(4))) float f32x4;
typedef __attribute__((ext_vector_type(8))) short short8;

__device__ __forceinline__ float bf2f(unsigned short u) {
    return __uint_as_float(((unsigned int)u) << 16);
}
__device__ __forceinline__ unsigned short f2bf(float f) {
    return __bfloat16_as_ushort(__float2bfloat16(f));
}

// ---------------------------------------------------------------------------
// Kernel 0: prep small weights — W_aug[d][64] = [W_e[d][0..49] | b_e[d] | 0...],
// emb_perm[tau][p] = emb[tau][delta(p)], both bf16.
// ---------------------------------------------------------------------------
__global__ __launch_bounds__(256)
void prep_w(const float* __restrict__ W_e, const float* __restrict__ b_e,
            const float* __restrict__ emb,
            unsigned short* __restrict__ W_aug, unsigned short* __restrict__ emb_perm)
{
    const int tid = blockIdx.x * 256 + threadIdx.x;
    if (tid < 128 * 64) {
        const int d = tid >> 6, k = tid & 63;
        float v = 0.0f;
        if (k < NRBF)       v = W_e[d * NRBF + k];
        else if (k == NRBF) v = b_e[d];
        W_aug[tid] = f2bf(v);
    } else if (tid < 128 * 64 + 100 * 128) {
        const int i = tid - 128 * 64;
        const int tau = i >> 7, p = i & 127;
        const int d = 16 * (p & 7) + (p >> 3);
        emb_perm[i] = f2bf(emb[tau * DIM + d]);
    }
}

// ---------------------------------------------------------------------------
// Kernel 1: bucket active edges by dst; emit cc[e] and embrow[e] (-1 inactive).
// ---------------------------------------------------------------------------
__global__ __launch_bounds__(256)
void build_buckets(const int* __restrict__ dst, const float* __restrict__ dist,
                   const int* __restrict__ src, const int* __restrict__ node_type,
                   int* __restrict__ deg, int* __restrict__ eid,
                   int* __restrict__ ovf, int* __restrict__ ovf_cnt,
                   float* __restrict__ cc_arr, int* __restrict__ embrow)
{
    const int e = blockIdx.x * 256 + threadIdx.x;
    if (e >= NE) return;
    const float dd = dist[e];
    const bool act = dd < CUT;
    const float w = 0.5f * (__cosf(dd * (PI_F / CUT)) + 1.0f);
    cc_arr[e] = act ? w : 0.0f;
    embrow[e] = act ? node_type[src[e]] : -1;
    if (act) {
        const int n = dst[e];
        const int pos = atomicAdd(&deg[n], 1);
        if (pos < CAP) eid[n * CAP + pos] = e;
        else           ovf[atomicAdd(ovf_cnt, 1)] = e;
    }
}

// ---------------------------------------------------------------------------
// Kernel 2: edge message via MFMA, NO LDS / NO barriers.
// B-fragments (W_aug) register-resident per lane; A-fragments built in-register
// from global rbf with cc folded in (k50 = cc -> acc = cc*(dot + b_e)).
// Epilogue: acc * emb_perm row (one 16 B load), one int4 store per edge-row.
// ---------------------------------------------------------------------------
__global__ __launch_bounds__(256)
void edge_msg_reg(const float* __restrict__ rbf,
                  const float* __restrict__ cc_arr,
                  const int* __restrict__ embrow,
                  const unsigned short* __restrict__ W_aug,
                  const unsigned short* __restrict__ emb_perm,
                  unsigned short* __restrict__ msg)
{
    const int t  = threadIdx.x;
    const int wv = t >> 6, l = t & 63;
    const int c  = l & 15, g = l >> 4;

    // B fragments: row nt*16+c of W_aug, k-chunk [s*32+g*8 .. +7]. 16 KB, L2-hot.
    short8 bfrag[16];
    #pragma unroll
    for (int nt = 0; nt < 8; ++nt)
        #pragma unroll
        for (int s = 0; s < 2; ++s)
            bfrag[nt * 2 + s] =
                *(const short8*)(W_aug + (nt * 16 + c) * 64 + s * 32 + g * 8);

    #pragma unroll
    for (int tile = 0; tile < 4; ++tile) {
        const int e0 = (blockIdx.x * 4 + tile) * 64;
        if (e0 < NE) {
            const int er = e0 + wv * 16 + c;         // this lane's A row (edge)
            const float ccl = cc_arr[er];            // 4 lanes/addr -> broadcast
            const float* rp = rbf + (size_t)er * NRBF;

            // epilogue metadata early (independent loads)
            int erow[4];
            #pragma unroll
            for (int r = 0; r < 4; ++r)
                erow[r] = embrow[e0 + wv * 16 + 4 * g + r];

            // A raw loads (8 B aligned: row stride 200 B)
            const float2 r0 = *(const float2*)(rp + 8 * g);
            const float2 r1 = *(const float2*)(rp + 8 * g + 2);
            const float2 r2 = *(const float2*)(rp + 8 * g + 4);
            const float2 r3 = *(const float2*)(rp + 8 * g + 6);
            float2 q0 = make_float2(0.f, 0.f), q1 = q0, q2 = q0, q3 = q0;
            if (g < 2) {
                q0 = *(const float2*)(rp + 32 + 8 * g);
                q1 = *(const float2*)(rp + 32 + 8 * g + 2);
                q2 = *(const float2*)(rp + 32 + 8 * g + 4);
                q3 = *(const float2*)(rp + 32 + 8 * g + 6);
            } else if (g == 2) {
                q0 = *(const float2*)(rp + 48);      // k48,k49
            }

            short8 a0, a1;
            a0[0] = (short)f2bf(ccl * r0.x); a0[1] = (short)f2bf(ccl * r0.y);
            a0[2] = (short)f2bf(ccl * r1.x); a0[3] = (short)f2bf(ccl * r1.y);
            a0[4] = (short)f2bf(ccl * r2.x); a0[5] = (short)f2bf(ccl * r2.y);
            a0[6] = (short)f2bf(ccl * r3.x); a0[7] = (short)f2bf(ccl * r3.y);
            a1[0] = (short)f2bf(ccl * q0.x); a1[1] = (short)f2bf(ccl * q0.y);
            a1[2] = (short)f2bf(ccl * q1.x); a1[3] = (short)f2bf(ccl * q1.y);
            a1[4] = (short)f2bf(ccl * q2.x); a1[5] = (short)f2bf(ccl * q2.y);
            a1[6] = (short)f2bf(ccl * q3.x); a1[7] = (short)f2bf(ccl * q3.y);
            if (g == 2) {                            // k50 = cc (b_e hook), k51+ = 0
                a1[2] = (short)f2bf(ccl);
                a1[3] = 0; a1[4] = 0; a1[5] = 0; a1[6] = 0; a1[7] = 0;
            }

            f32x4 acc[8] = {};
            #pragma unroll
            for (int nt = 0; nt < 8; ++nt)
                acc[nt] = __builtin_amdgcn_mfma_f32_16x16x32_bf16(a0, bfrag[nt * 2],
                                                                  acc[nt], 0, 0, 0);
            #pragma unroll
            for (int nt = 0; nt < 8; ++nt)
                acc[nt] = __builtin_amdgcn_mfma_f32_16x16x32_bf16(a1, bfrag[nt * 2 + 1],
                                                                  acc[nt], 0, 0, 0);

            // Epilogue: lane owns D col c for rows 4g..4g+3 of its wave strip.
            #pragma unroll
            for (int r = 0; r < 4; ++r) {
                const int e = e0 + wv * 16 + 4 * g + r;
                const int rw = erow[r];
                if (rw >= 0) {                       // active edge: store (zeros included)
                    const int4 em = *(const int4*)(emb_perm + rw * DIM + 8 * c);
                    const unsigned int* ep = (const unsigned int*)&em;
                    unsigned int ow[4];
                    #pragma unroll
                    for (int q = 0; q < 4; ++q) {
                        const float m0 = bf2f((unsigned short)(ep[q] & 0xffff));
                        const float m1 = bf2f((unsigned short)(ep[q] >> 16));
                        const float v0 = acc[2 * q][r] * m0;
                        const float v1 = acc[2 * q + 1][r] * m1;
                        ow[q] = (unsigned int)f2bf(v0) | ((unsigned int)f2bf(v1) << 16);
                    }
                    *(int4*)(msg + (size_t)e * DIM + 8 * c) =
                        make_int4((int)ow[0], (int)ow[1], (int)ow[2], (int)ow[3]);
                }
            }
        }
    }
}

// ---------------------------------------------------------------------------
// Kernel 3: gather-sum. 1 wave/node; lane group g handles edge j+g; lane loads
// int4 (16 B) of the permuted row; butterfly reduce over groups; store xi in
// NORMAL dim order (lane (c,g) -> dims 32g+c, 32g+16+c).
// ---------------------------------------------------------------------------
__global__ __launch_bounds__(256)
void gather_sum(const unsigned short* __restrict__ msg, const int* __restrict__ deg,
                const int* __restrict__ eid, const int* __restrict__ ovf,
                const int* __restrict__ ovf_cnt, const int* __restrict__ dst,
                unsigned short* __restrict__ xi)
{
    const int t = threadIdx.x, l = t & 63;
    const int c = l & 15, g = l >> 4;
    const int n = blockIdx.x * 4 + (t >> 6);
    if (n >= NN) return;

    const int dn   = deg[n];
    const int degn = dn < CAP ? dn : CAP;
    int eidv = 0;
    if (l < degn) eidv = eid[n * CAP + l];

    float v[8] = {};
    for (int j = 0; j < degn; j += 4) {
        const int e = __shfl(eidv, j + g);
        if (j + g < degn) {
            const int4 mv = *(const int4*)(msg + (size_t)e * DIM + 8 * c);
            const unsigned int* mp = (const unsigned int*)&mv;
            #pragma unroll
            for (int q = 0; q < 4; ++q) {
                v[2 * q]     += bf2f((unsigned short)(mp[q] & 0xffff));
                v[2 * q + 1] += bf2f((unsigned short)(mp[q] >> 16));
            }
        }
    }
    // Overflow fallback (deg > CAP): essentially never taken, kept for correctness.
    const int ocnt = ovf_cnt[0];
    for (int j = 0; j < ocnt; ++j) {
        const int e = ovf[j];
        if (g == 0 && dst[e] == n) {   // single group accumulates; butterfly counts once
            const int4 mv = *(const int4*)(msg + (size_t)e * DIM + 8 * c);
            const unsigned int* mp = (const unsigned int*)&mv;
            #pragma unroll
            for (int q = 0; q < 4; ++q) {
                v[2 * q]     += bf2f((unsigned short)(mp[q] & 0xffff));
                v[2 * q + 1] += bf2f((unsigned short)(mp[q] >> 16));
            }
        }
    }

    #pragma unroll
    for (int q = 0; q < 8; ++q) {
        v[q] += __shfl_xor(v[q], 16);
        v[q] += __shfl_xor(v[q], 32);
    }

    // lane (c,g): position 8c+q holds dim 16q+c; store q = 2g, 2g+1.
    float s0 = v[0], s1 = v[1];
    if (g == 1)      { s0 = v[2]; s1 = v[3]; }
    else if (g == 2) { s0 = v[4]; s1 = v[5]; }
    else if (g == 3) { s0 = v[6]; s1 = v[7]; }
    xi[(size_t)n * DIM + 32 * g + c]      = f2bf(s0);
    xi[(size_t)n * DIM + 32 * g + 16 + c] = f2bf(s1);
}

// ---------------------------------------------------------------------------
// Kernel 4: out[n] = [x_nodes[n] | xi[n]] @ W_c^T + b_c  via bf16 MFMA.
// (unchanged from R5 — known good)
// ---------------------------------------------------------------------------
__global__ __launch_bounds__(256)
void combine_mfma(const float* __restrict__ x_nodes, const __hip_bfloat16* __restrict__ xi,
                  const float* __restrict__ W_c, const float* __restrict__ b_c,
                  float* __restrict__ out)
{
    __shared__ unsigned short As[64][72];
    __shared__ unsigned short Bs[128][72];

    const int t  = threadIdx.x;
    const int wv = t >> 6;
    const int l  = t & 63;
    const int n0 = blockIdx.x * 64;

    f32x4 acc[8] = {};

    for (int kc = 0; kc < 4; ++kc) {
        const int kb = kc * 64;
        if (kc) __syncthreads();
        {
            const int r  = t >> 2;
            const int c0 = (t & 3) * 16;
            const int n  = n0 + r;
            if (kc < 2) {
                float4 v[4];
                if (n < NN) {
                    const float4* p = (const float4*)(x_nodes + (size_t)n * DIM + kb + c0);
                    v[0] = p[0]; v[1] = p[1]; v[2] = p[2]; v[3] = p[3];
                } else {
                    v[0] = v[1] = v[2] = v[3] = make_float4(0.f, 0.f, 0.f, 0.f);
                }
                unsigned short* dp = &As[r][c0];
                #pragma unroll
                for (int q = 0; q < 4; ++q) {
                    *(ushort2*)&dp[q * 4]     = make_ushort2(f2bf(v[q].x), f2bf(v[q].y));
                    *(ushort2*)&dp[q * 4 + 2] = make_ushort2(f2bf(v[q].z), f2bf(v[q].w));
                }
            } else {
                int4 v0 = make_int4(0, 0, 0, 0), v1 = make_int4(0, 0, 0, 0);
                if (n < NN) {
                    const int4* p = (const int4*)(xi + (size_t)n * DIM + (kb - DIM) + c0);
                    v0 = p[0];
                    v1 = p[1];
                }
                *(int4*)&As[r][c0]     = v0;
                *(int4*)&As[r][c0 + 8] = v1;
            }
        }
        {
            const int dch = t >> 1;
            const int c0  = (t & 1) * 32;
            const float4* p = (const float4*)(W_c + (size_t)dch * (2 * DIM) + kb + c0);
            unsigned short* dp = &Bs[dch][c0];
            #pragma unroll
            for (int q = 0; q < 8; ++q) {
                const float4 v = p[q];
                *(ushort2*)&dp[q * 4]     = make_ushort2(f2bf(v.x), f2bf(v.y));
                *(ushort2*)&dp[q * 4 + 2] = make_ushort2(f2bf(v.z), f2bf(v.w));
            }
        }
        __syncthreads();
        #pragma unroll
        for (int s = 0; s < 2; ++s) {
            const int ko = s * 32 + (l >> 4) * 8;
            const short8 af = *(const short8*)&As[wv * 16 + (l & 15)][ko];
            #pragma unroll
            for (int nt = 0; nt < 8; ++nt) {
                const short8 bf = *(const short8*)&Bs[nt * 16 + (l & 15)][ko];
                acc[nt] = __builtin_amdgcn_mfma_f32_16x16x32_bf16(af, bf, acc[nt], 0, 0, 0);
            }
        }
    }

    const int col = l & 15;
    const int rq  = (l >> 4) * 4;
    #pragma unroll
    for (int nt = 0; nt < 8; ++nt) {
        const int dim = nt * 16 + col;
        const float bc = b_c[dim];
        #pragma unroll
        for (int r = 0; r < 4; ++r) {
            const int node = n0 + wv * 16 + rq + r;
            if (node < NN)
                out[(size_t)node * DIM + dim] = acc[nt][r] + bc;
        }
    }
}

// ---------------------------------------------------------------------------
extern "C" void kernel_launch(void* const* d_in, const int* in_sizes, int n_in,
                              void* d_out, int out_size, void* d_ws, size_t ws_size,
                              hipStream_t stream)
{
    const int*   node_type = (const int*)  d_in[0];
    const float* x_nodes   = (const float*)d_in[1];
    const int*   src       = (const int*)  d_in[2];
    const int*   dst       = (const int*)  d_in[3];
    const float* rbf       = (const float*)d_in[4];
    const float* dist      = (const float*)d_in[5];
    const float* emb       = (const float*)d_in[6];
    const float* W_e       = (const float*)d_in[7];
    const float* b_e       = (const float*)d_in[8];
    const float* W_c       = (const float*)d_in[9];
    const float* b_c       = (const float*)d_in[10];
    float* out = (float*)d_out;

    char* ws = (char*)d_ws;
    int*            deg      = (int*)(ws + OFF_DEG);
    int*            ovf_cnt  = (int*)(ws + OFF_OVFC);
    int*            eid      = (int*)(ws + OFF_EID);
    int*            ovf      = (int*)(ws + OFF_OVF);
    float*          cc_arr   = (float*)(ws + OFF_CC);
    int*            embrow   = (int*)(ws + OFF_EROW);
    unsigned short* W_aug    = (unsigned short*)(ws + OFF_WAUG);
    unsigned short* emb_perm = (unsigned short*)(ws + OFF_EPERM);
    unsigned short* msg      = (unsigned short*)(ws + OFF_MSG);
    unsigned short* xi       = (unsigned short*)(ws + OFF_XI);

    hipMemsetAsync(deg, 0, (NN + 1) * sizeof(int), stream);

    prep_w<<<82, 256, 0, stream>>>(W_e, b_e, emb, W_aug, emb_perm);

    build_buckets<<<(NE + 255) / 256, 256, 0, stream>>>(
        dst, dist, src, node_type, deg, eid, ovf, ovf_cnt, cc_arr, embrow);

    edge_msg_reg<<<(NE / 64 + 3) / 4, 256, 0, stream>>>(
        rbf, cc_arr, embrow, W_aug, emb_perm, msg);

    gather_sum<<<(NN + 3) / 4, 256, 0, stream>>>(msg, deg, eid, ovf, ovf_cnt, dst, xi);

    combine_mfma<<<(NN + 63) / 64, 256, 0, stream>>>(
        x_nodes, (const __hip_bfloat16*)xi, W_c, b_c, out);
}